// Round 8
// baseline (755.721 us; speedup 1.0000x reference)
//
#include <hip/hip_runtime.h>

#define NSEQ 2048
#define DMODEL 1024
#define NHEAD 16
#define HDIM 64
#define NBATCH 4
#define MTOT 8192
#define ATT_SCALE 0.125f
#define LOG2E 1.4426950408889634f
#define SM_SHIFT 12.0f

typedef __bf16 bf16x8 __attribute__((ext_vector_type(8)));
typedef float f32x4 __attribute__((ext_vector_type(4)));
typedef unsigned int u32x4 __attribute__((ext_vector_type(4)));
typedef unsigned short u16;
typedef unsigned int u32;
typedef unsigned long long u64;

__device__ __forceinline__ u16 f2bf(float f) {
  u32 u = __builtin_bit_cast(u32, f);
  return (u16)((u + 0x7fffu + ((u >> 16) & 1u)) >> 16);
}

__device__ __forceinline__ void gload_lds16(const void* g, void* l) {
  __builtin_amdgcn_global_load_lds(
      (__attribute__((address_space(1))) const u32*)g,
      (__attribute__((address_space(3))) u32*)l, 16, 0, 0);
}

// ---------------- cast fp32 -> bf16 (x) ----------------
__global__ __launch_bounds__(256) void cast_f32_bf16(const float* __restrict__ in,
                                                     u16* __restrict__ out, int n) {
  int i = (blockIdx.x * 256 + threadIdx.x) * 4;
  if (i >= n) return;
  float4 v = *(const float4*)(in + i);
  ushort4 o;
  o.x = f2bf(v.x); o.y = f2bf(v.y); o.z = f2bf(v.z); o.w = f2bf(v.w);
  *(ushort4*)(out + i) = o;
}

// ---------------- cast 4 weights -> contiguous bf16 block ----------------
__global__ __launch_bounds__(256) void cast_w4(const float* __restrict__ a,
                                               const float* __restrict__ b,
                                               const float* __restrict__ c,
                                               const float* __restrict__ d,
                                               u16* __restrict__ out) {
  int bid = blockIdx.x;
  int which = bid >> 10, lb = bid & 1023;
  const float* src = (which == 0) ? a : (which == 1) ? b : (which == 2) ? c : d;
  int i = (lb * 256 + threadIdx.x) * 4;
  float4 v = *(const float4*)(src + i);
  ushort4 o;
  o.x = f2bf(v.x); o.y = f2bf(v.y); o.z = f2bf(v.z); o.w = f2bf(v.w);
  *(ushort4*)(out + (size_t)which * 1048576 + i) = o;
}

// ---------------- pack mask int32 -> bit per element ----------------
__global__ __launch_bounds__(256) void pack_mask(const int* __restrict__ mask,
                                                 u64* __restrict__ bits) {
  int wave = (blockIdx.x * 256 + threadIdx.x) >> 6;
  int lane = threadIdx.x & 63;
  const int* row = mask + (size_t)wave * NSEQ;
  u64* out = bits + (size_t)wave * 32;
  for (int c = 0; c < 32; ++c) {
    int v = row[c * 64 + lane];
    u64 bl = __ballot(v != 0);
    if (lane == 0) out[c] = bl;
  }
}

// ---------------- fused QKV GEMM: C[m,n] = sum_k A[m,k]*Wc[n,k], N=3072 ----------------
// bn 0..7 -> Q [B,H,N,64]; 8..15 -> K [B,H,N,64]; 16..23 -> V^T [B,H,64,NSEQ]
__global__ __launch_bounds__(256) void gemm_qkv(const u16* __restrict__ A,
                                                const u16* __restrict__ Wc,
                                                u16* __restrict__ qo,
                                                u16* __restrict__ ko,
                                                u16* __restrict__ vo) {
  __shared__ __align__(16) u16 Al[128 * 64];
  __shared__ __align__(16) u16 Bl[128 * 64];
  const int tid = threadIdx.x;
  const int w = tid >> 6, l = tid & 63;
  const int l15 = l & 15, l4 = l >> 4;
  const int bm = blockIdx.x, bn = blockIdx.y;
  const int wm = w >> 1, wn = w & 1;

  f32x4 acc[4][4] = {};

  for (int ks = 0; ks < 1024; ks += 64) {
    __syncthreads();
#pragma unroll
    for (int c = 0; c < 4; ++c) {
      int g = w * 256 + c * 64 + l;
      int row = g >> 3, gc = g & 7;
      int sgc = gc ^ (row & 7);
      gload_lds16(A + (size_t)(bm * 128 + row) * 1024 + ks + sgc * 8, &Al[g * 8]);
      gload_lds16(Wc + (size_t)(bn * 128 + row) * 1024 + ks + sgc * 8, &Bl[g * 8]);
    }
    __syncthreads();
#pragma unroll
    for (int kc = 0; kc < 2; ++kc) {
      bf16x8 af[4], bfr[4];
#pragma unroll
      for (int mi = 0; mi < 4; ++mi) {
        int row = wm * 64 + mi * 16 + l15;
        int gc2 = (kc * 4 + l4) ^ (row & 7);
        af[mi] = *(const bf16x8*)&Al[row * 64 + gc2 * 8];
      }
#pragma unroll
      for (int ni = 0; ni < 4; ++ni) {
        int row = wn * 64 + ni * 16 + l15;
        int gc2 = (kc * 4 + l4) ^ (row & 7);
        bfr[ni] = *(const bf16x8*)&Bl[row * 64 + gc2 * 8];
      }
#pragma unroll
      for (int mi = 0; mi < 4; ++mi)
#pragma unroll
        for (int ni = 0; ni < 4; ++ni)
          acc[mi][ni] = __builtin_amdgcn_mfma_f32_16x16x32_bf16(af[mi], bfr[ni],
                                                                acc[mi][ni], 0, 0, 0);
    }
  }

  const int which = bn >> 3;
#pragma unroll
  for (int mi = 0; mi < 4; ++mi)
#pragma unroll
    for (int ni = 0; ni < 4; ++ni)
#pragma unroll
      for (int r = 0; r < 4; ++r) {
        int m = bm * 128 + wm * 64 + mi * 16 + l4 * 4 + r;
        int n = (bn & 7) * 128 + wn * 64 + ni * 16 + l15;
        int b = m >> 11, row = m & 2047, h = n >> 6, d = n & 63;
        u16 val = f2bf(acc[mi][ni][r]);
        size_t bh = (size_t)(b * 16 + h);
        if (which == 0)      qo[(bh * NSEQ + row) * 64 + d] = val;
        else if (which == 1) ko[(bh * NSEQ + row) * 64 + d] = val;
        else                 vo[(bh * 64 + d) * NSEQ + row] = val;
      }
}

// ---------------- final GEMM: out[m,n] = sum_k A[m,k]*W[n,k], fp32 out ----------------
__global__ __launch_bounds__(256) void gemm_out(const u16* __restrict__ A,
                                                const u16* __restrict__ W,
                                                float* __restrict__ C) {
  __shared__ __align__(16) u16 Al[128 * 64];
  __shared__ __align__(16) u16 Bl[128 * 64];
  const int tid = threadIdx.x;
  const int w = tid >> 6, l = tid & 63;
  const int l15 = l & 15, l4 = l >> 4;
  const int bm = blockIdx.x, bn = blockIdx.y;
  const int wm = w >> 1, wn = w & 1;

  f32x4 acc[4][4] = {};

  for (int ks = 0; ks < 1024; ks += 64) {
    __syncthreads();
#pragma unroll
    for (int c = 0; c < 4; ++c) {
      int g = w * 256 + c * 64 + l;
      int row = g >> 3, gc = g & 7;
      int sgc = gc ^ (row & 7);
      gload_lds16(A + (size_t)(bm * 128 + row) * 1024 + ks + sgc * 8, &Al[g * 8]);
      gload_lds16(W + (size_t)(bn * 128 + row) * 1024 + ks + sgc * 8, &Bl[g * 8]);
    }
    __syncthreads();
#pragma unroll
    for (int kc = 0; kc < 2; ++kc) {
      bf16x8 af[4], bfr[4];
#pragma unroll
      for (int mi = 0; mi < 4; ++mi) {
        int row = wm * 64 + mi * 16 + l15;
        int gc2 = (kc * 4 + l4) ^ (row & 7);
        af[mi] = *(const bf16x8*)&Al[row * 64 + gc2 * 8];
      }
#pragma unroll
      for (int ni = 0; ni < 4; ++ni) {
        int row = wn * 64 + ni * 16 + l15;
        int gc2 = (kc * 4 + l4) ^ (row & 7);
        bfr[ni] = *(const bf16x8*)&Bl[row * 64 + gc2 * 8];
      }
#pragma unroll
      for (int mi = 0; mi < 4; ++mi)
#pragma unroll
        for (int ni = 0; ni < 4; ++ni)
          acc[mi][ni] = __builtin_amdgcn_mfma_f32_16x16x32_bf16(af[mi], bfr[ni],
                                                                acc[mi][ni], 0, 0, 0);
    }
  }

#pragma unroll
  for (int mi = 0; mi < 4; ++mi)
#pragma unroll
    for (int ni = 0; ni < 4; ++ni)
#pragma unroll
      for (int r = 0; r < 4; ++r) {
        int m = bm * 128 + wm * 64 + mi * 16 + l4 * 4 + r;
        int n = bn * 128 + wn * 64 + ni * 16 + l15;
        C[(size_t)m * 1024 + n] = acc[mi][ni][r];
      }
}

// ---------------- flash attention: register-direct, ZERO LDS / ZERO barriers ----------------
// 256 thr = 4 waves x 16 q-rows (waves fully independent; same-addr K/V loads
// hit L1 broadcast; K/V/alibi-siblings L2-resident). KT=32 per body, 64 bodies.
// K rows loaded permuted (krow = 8*(l15>>2)+4kb+(l15&3)) so each lane's P
// k-slots are contiguous -> pa feeds PV directly, V loads unpermuted 16B rows,
// alibi = 2 float4/lane/body, mask = 1 dword. Fixed-shift softmax + MFMA
// ones-trick row sum: no cross-lane ops anywhere. Register double-buffer on
// K/V/alibi/mask (prefetch t+1 issued before compute t).
__global__ __launch_bounds__(256, 3) void attn_kernel(
    const u16* __restrict__ q, const u16* __restrict__ k, const u16* __restrict__ vT,
    const float* __restrict__ alibi, const u64* __restrict__ mbits,
    u16* __restrict__ o) {
  const int tid = threadIdx.x, w = tid >> 6, l = tid & 63;
  const int l15 = l & 15, l4 = l >> 4;
  const int W = blockIdx.x;
  const int W2 = (W & 7) * 256 + (W >> 3);
  // batch innermost: siblings b=0..3 adjacent -> alibi L2 reuse by construction
  const int b = W2 & 3, hq = W2 >> 2;
  const int qb = hq & 31, h = hq >> 5;
  const int bh = b * 16 + h;
  const int wq0 = qb * 64 + w * 16;
  const int myq = wq0 + l15;

  // Q fragment (B-operand: col q = l15, rows d = l4*8+j (+32 for dc=1))
  bf16x8 aq0, aq1;
  {
    const u16* qrow = q + ((size_t)bh * NSEQ + myq) * 64;
    aq0 = *(const bf16x8*)(qrow + l4 * 8);
    aq1 = *(const bf16x8*)(qrow + 32 + l4 * 8);
  }

  // K base (A-operand row x=l15 -> permuted global row 8*(x>>2)+(x&3); kb -> +4 rows)
  const u16* kp = k + ((size_t)bh * NSEQ + 8 * (l15 >> 2) + (l15 & 3)) * 64 + l4 * 8;
  // V ptrs per db (B-operand: col d = db*16+l15, rows k = 8*l4+j, unpermuted)
  const u16* vp0 = vT + ((size_t)bh * 64 +  0 + l15) * NSEQ + 8 * l4;
  const u16* vp1 = vT + ((size_t)bh * 64 + 16 + l15) * NSEQ + 8 * l4;
  const u16* vp2 = vT + ((size_t)bh * 64 + 32 + l15) * NSEQ + 8 * l4;
  const u16* vp3 = vT + ((size_t)bh * 64 + 48 + l15) * NSEQ + 8 * l4;
  // alibi: lane's 8 contiguous k at 8*l4 (thanks to the K permutation)
  const float* alp = alibi + (size_t)h * NSEQ * NSEQ + (size_t)myq * NSEQ + 8 * l4;
  const u32* mp = (const u32*)(mbits + ((size_t)b * NSEQ + myq) * 32);

  const u32x4 onesu = {0x3F803F80u, 0x3F803F80u, 0x3F803F80u, 0x3F803F80u};
  const bf16x8 bones = __builtin_bit_cast(bf16x8, onesu);

  f32x4 oacc0 = {}, oacc1 = {}, oacc2 = {}, oacc3 = {};
  f32x4 osum = {};

  bf16x8 kA00, kA01, kA10, kA11, kB00, kB01, kB10, kB11;
  bf16x8 vA0, vA1, vA2, vA3, vB0, vB1, vB2, vB3;
  float4 alA0, alA1, alB0, alB1;
  u32 mwA, mwB;

#define LDK(s0, s1, s2, s3)                         \
  s0 = *(const bf16x8*)(kp);                        \
  s1 = *(const bf16x8*)(kp + 32);                   \
  s2 = *(const bf16x8*)(kp + 256);                  \
  s3 = *(const bf16x8*)(kp + 288);                  \
  kp += 2048;
#define LDV(d0, d1, d2, d3)                         \
  d0 = *(const bf16x8*)(vp0); vp0 += 32;            \
  d1 = *(const bf16x8*)(vp1); vp1 += 32;            \
  d2 = *(const bf16x8*)(vp2); vp2 += 32;            \
  d3 = *(const bf16x8*)(vp3); vp3 += 32;
#define LDA(a0, a1, mw)                             \
  a0 = *(const float4*)(alp);                       \
  a1 = *(const float4*)(alp + 4);                   \
  alp += 32;                                        \
  mw = *mp++;

#define COMPUTE(kc00, kc01, kc10, kc11, vc0, vc1, vc2, vc3, ac0, ac1, mwc)     \
  {                                                                            \
    f32x4 z = {0.f, 0.f, 0.f, 0.f};                                            \
    f32x4 st0 = __builtin_amdgcn_mfma_f32_16x16x32_bf16(kc00, aq0, z, 0, 0, 0);\
    st0 = __builtin_amdgcn_mfma_f32_16x16x32_bf16(kc01, aq1, st0, 0, 0, 0);    \
    f32x4 st1 = __builtin_amdgcn_mfma_f32_16x16x32_bf16(kc10, aq0, z, 0, 0, 0);\
    st1 = __builtin_amdgcn_mfma_f32_16x16x32_bf16(kc11, aq1, st1, 0, 0, 0);    \
    float p[8];                                                                \
    _Pragma("unroll")                                                          \
    for (int r = 0; r < 4; ++r) {                                              \
      p[r]     = fmaf(st0[r], ATT_SCALE, ac0[r]);                              \
      p[4 + r] = fmaf(st1[r], ATT_SCALE, ac1[r]);                              \
    }                                                                          \
    if (!__all(mwc == 0xFFFFFFFFu)) {                                          \
      _Pragma("unroll")                                                        \
      for (int j = 0; j < 8; ++j)                                              \
        if (!((mwc >> (8 * l4 + j)) & 1)) p[j] = -3.0e38f;                     \
    }                                                                          \
    _Pragma("unroll")                                                          \
    for (int j = 0; j < 8; ++j)                                                \
      p[j] = exp2f(fmaf(p[j], LOG2E, -SM_SHIFT * LOG2E));                      \
    u32 Wp0, Wp1, Wp2, Wp3;                                                    \
    asm("v_cvt_pk_bf16_f32 %0, %1, %2" : "=v"(Wp0) : "v"(p[0]), "v"(p[1]));    \
    asm("v_cvt_pk_bf16_f32 %0, %1, %2" : "=v"(Wp1) : "v"(p[2]), "v"(p[3]));    \
    asm("v_cvt_pk_bf16_f32 %0, %1, %2" : "=v"(Wp2) : "v"(p[4]), "v"(p[5]));    \
    asm("v_cvt_pk_bf16_f32 %0, %1, %2" : "=v"(Wp3) : "v"(p[6]), "v"(p[7]));    \
    u32x4 wv = {Wp0, Wp1, Wp2, Wp3};                                           \
    bf16x8 pa = __builtin_bit_cast(bf16x8, wv);                                \
    osum = __builtin_amdgcn_mfma_f32_16x16x32_bf16(pa, bones, osum, 0, 0, 0);  \
    oacc0 = __builtin_amdgcn_mfma_f32_16x16x32_bf16(pa, vc0, oacc0, 0, 0, 0);  \
    oacc1 = __builtin_amdgcn_mfma_f32_16x16x32_bf16(pa, vc1, oacc1, 0, 0, 0);  \
    oacc2 = __builtin_amdgcn_mfma_f32_16x16x32_bf16(pa, vc2, oacc2, 0, 0, 0);  \
    oacc3 = __builtin_amdgcn_mfma_f32_16x16x32_bf16(pa, vc3, oacc3, 0, 0, 0);  \
  }

  // prologue: t=0 into A set
  LDK(kA00, kA01, kA10, kA11)
  LDV(vA0, vA1, vA2, vA3)
  LDA(alA0, alA1, mwA)

  for (int t2 = 0; t2 < 31; ++t2) {
    LDK(kB00, kB01, kB10, kB11)
    LDV(vB0, vB1, vB2, vB3)
    LDA(alB0, alB1, mwB)
    COMPUTE(kA00, kA01, kA10, kA11, vA0, vA1, vA2, vA3, alA0, alA1, mwA)
    LDK(kA00, kA01, kA10, kA11)
    LDV(vA0, vA1, vA2, vA3)
    LDA(alA0, alA1, mwA)
    COMPUTE(kB00, kB01, kB10, kB11, vB0, vB1, vB2, vB3, alB0, alB1, mwB)
  }
  // peel: t=62 (prefetch 63), t=63 (no prefetch)
  LDK(kB00, kB01, kB10, kB11)
  LDV(vB0, vB1, vB2, vB3)
  LDA(alB0, alB1, mwB)
  COMPUTE(kA00, kA01, kA10, kA11, vA0, vA1, vA2, vA3, alA0, alA1, mwA)
  COMPUTE(kB00, kB01, kB10, kB11, vB0, vB1, vB2, vB3, alB0, alB1, mwB)

  // normalize + write O (q = wq0 + l4*4 + r, d = db*16 + l15); no shfl needed
  f32x4 oa[4] = {oacc0, oacc1, oacc2, oacc3};
#pragma unroll
  for (int r = 0; r < 4; ++r) {
    float inv = __builtin_amdgcn_rcpf(osum[r]);
    int qq = wq0 + l4 * 4 + r;
#pragma unroll
    for (int db = 0; db < 4; ++db) {
      int d = db * 16 + l15;
      o[((size_t)b * NSEQ + qq) * DMODEL + h * 64 + d] = f2bf(oa[db][r] * inv);
    }
  }
#undef LDK
#undef LDV
#undef LDA
#undef COMPUTE
}

extern "C" void kernel_launch(void* const* d_in, const int* in_sizes, int n_in,
                              void* d_out, int out_size, void* d_ws, size_t ws_size,
                              hipStream_t stream) {
  (void)in_sizes; (void)n_in; (void)out_size; (void)ws_size;
  const float* x = (const float*)d_in[0];
  const int* mask = (const int*)d_in[1];
  const float* alibi = (const float*)d_in[2];
  const float* Wq = (const float*)d_in[3];
  const float* Wk = (const float*)d_in[4];
  const float* Wv = (const float*)d_in[5];
  const float* Wo = (const float*)d_in[6];
  float* out = (float*)d_out;

  char* ws = (char*)d_ws;
  const size_t MB = 1u << 20;
  u16* xb  = (u16*)(ws + 0 * MB);    // 16 MB
  u16* wqb = (u16*)(ws + 16 * MB);   // 8 MB (wq,wk,wv,wo contiguous)
  u16* wob = (u16*)(ws + 22 * MB);
  u16* qb  = (u16*)(ws + 24 * MB);   // 16 MB  [B,H,N,64]
  u16* kb  = (u16*)(ws + 40 * MB);   // 16 MB  [B,H,N,64]
  u16* vT  = (u16*)(ws + 56 * MB);   // 16 MB  [B,H,64,N]
  u16* ob  = (u16*)(ws + 72 * MB);   // 16 MB  [B,N,1024]
  u64* mbits = (u64*)(ws + 88 * MB); // 2 MB   [B*N][32]

  cast_f32_bf16<<<8192, 256, 0, stream>>>(x, xb, MTOT * DMODEL);
  cast_w4<<<4096, 256, 0, stream>>>(Wq, Wk, Wv, Wo, wqb);
  pack_mask<<<2048, 256, 0, stream>>>(mask, mbits);

  gemm_qkv<<<dim3(64, 24), 256, 0, stream>>>(xb, wqb, qb, kb, vT);

  attn_kernel<<<2048, 256, 0, stream>>>(qb, kb, vT, alibi, mbits, ob);

  gemm_out<<<dim3(64, 8), 256, 0, stream>>>(ob, wob, out);
}

// Round 9
// 376.990 us; speedup vs baseline: 2.0046x; 2.0046x over previous
//
#include <hip/hip_runtime.h>

#define NSEQ 2048
#define DMODEL 1024
#define NHEAD 16
#define HDIM 64
#define NBATCH 4
#define MTOT 8192
#define ATT_SCALE 0.125f
#define LOG2E 1.4426950408889634f

typedef __bf16 bf16x8 __attribute__((ext_vector_type(8)));
typedef float f32x4 __attribute__((ext_vector_type(4)));
typedef unsigned int u32x4 __attribute__((ext_vector_type(4)));
typedef unsigned short u16;
typedef unsigned int u32;
typedef unsigned long long u64;

__device__ __forceinline__ u16 f2bf(float f) {
  u32 u = __builtin_bit_cast(u32, f);
  return (u16)((u + 0x7fffu + ((u >> 16) & 1u)) >> 16);
}

__device__ __forceinline__ void gload_lds16(const void* g, void* l) {
  __builtin_amdgcn_global_load_lds(
      (__attribute__((address_space(1))) const u32*)g,
      (__attribute__((address_space(3))) u32*)l, 16, 0, 0);
}

// ---------------- cast fp32 -> bf16 (x) ----------------
__global__ __launch_bounds__(256) void cast_f32_bf16(const float* __restrict__ in,
                                                     u16* __restrict__ out, int n) {
  int i = (blockIdx.x * 256 + threadIdx.x) * 4;
  if (i >= n) return;
  float4 v = *(const float4*)(in + i);
  ushort4 o;
  o.x = f2bf(v.x); o.y = f2bf(v.y); o.z = f2bf(v.z); o.w = f2bf(v.w);
  *(ushort4*)(out + i) = o;
}

// ---------------- cast 4 weights -> contiguous bf16 block ----------------
__global__ __launch_bounds__(256) void cast_w4(const float* __restrict__ a,
                                               const float* __restrict__ b,
                                               const float* __restrict__ c,
                                               const float* __restrict__ d,
                                               u16* __restrict__ out) {
  int bid = blockIdx.x;
  int which = bid >> 10, lb = bid & 1023;
  const float* src = (which == 0) ? a : (which == 1) ? b : (which == 2) ? c : d;
  int i = (lb * 256 + threadIdx.x) * 4;
  float4 v = *(const float4*)(src + i);
  ushort4 o;
  o.x = f2bf(v.x); o.y = f2bf(v.y); o.z = f2bf(v.z); o.w = f2bf(v.w);
  *(ushort4*)(out + (size_t)which * 1048576 + i) = o;
}

// ---------------- pack mask int32 -> bit per element ----------------
__global__ __launch_bounds__(256) void pack_mask(const int* __restrict__ mask,
                                                 u64* __restrict__ bits) {
  int wave = (blockIdx.x * 256 + threadIdx.x) >> 6;
  int lane = threadIdx.x & 63;
  const int* row = mask + (size_t)wave * NSEQ;
  u64* out = bits + (size_t)wave * 32;
  for (int c = 0; c < 32; ++c) {
    int v = row[c * 64 + lane];
    u64 bl = __ballot(v != 0);
    if (lane == 0) out[c] = bl;
  }
}

// ---------------- fused QKV GEMM: C[m,n] = sum_k A[m,k]*Wc[n,k], N=3072 ----------------
// bn 0..7 -> Q [B,H,N,64]; 8..15 -> K [B,H,N,64]; 16..23 -> V^T [B,H,64,NSEQ]
__global__ __launch_bounds__(256) void gemm_qkv(const u16* __restrict__ A,
                                                const u16* __restrict__ Wc,
                                                u16* __restrict__ qo,
                                                u16* __restrict__ ko,
                                                u16* __restrict__ vo) {
  __shared__ __align__(16) u16 Al[128 * 64];
  __shared__ __align__(16) u16 Bl[128 * 64];
  const int tid = threadIdx.x;
  const int w = tid >> 6, l = tid & 63;
  const int l15 = l & 15, l4 = l >> 4;
  const int bm = blockIdx.x, bn = blockIdx.y;
  const int wm = w >> 1, wn = w & 1;

  f32x4 acc[4][4] = {};

  for (int ks = 0; ks < 1024; ks += 64) {
    __syncthreads();
#pragma unroll
    for (int c = 0; c < 4; ++c) {
      int g = w * 256 + c * 64 + l;
      int row = g >> 3, gc = g & 7;
      int sgc = gc ^ (row & 7);
      gload_lds16(A + (size_t)(bm * 128 + row) * 1024 + ks + sgc * 8, &Al[g * 8]);
      gload_lds16(Wc + (size_t)(bn * 128 + row) * 1024 + ks + sgc * 8, &Bl[g * 8]);
    }
    __syncthreads();
#pragma unroll
    for (int kc = 0; kc < 2; ++kc) {
      bf16x8 af[4], bfr[4];
#pragma unroll
      for (int mi = 0; mi < 4; ++mi) {
        int row = wm * 64 + mi * 16 + l15;
        int gc2 = (kc * 4 + l4) ^ (row & 7);
        af[mi] = *(const bf16x8*)&Al[row * 64 + gc2 * 8];
      }
#pragma unroll
      for (int ni = 0; ni < 4; ++ni) {
        int row = wn * 64 + ni * 16 + l15;
        int gc2 = (kc * 4 + l4) ^ (row & 7);
        bfr[ni] = *(const bf16x8*)&Bl[row * 64 + gc2 * 8];
      }
#pragma unroll
      for (int mi = 0; mi < 4; ++mi)
#pragma unroll
        for (int ni = 0; ni < 4; ++ni)
          acc[mi][ni] = __builtin_amdgcn_mfma_f32_16x16x32_bf16(af[mi], bfr[ni],
                                                                acc[mi][ni], 0, 0, 0);
    }
  }

  const int which = bn >> 3;
#pragma unroll
  for (int mi = 0; mi < 4; ++mi)
#pragma unroll
    for (int ni = 0; ni < 4; ++ni)
#pragma unroll
      for (int r = 0; r < 4; ++r) {
        int m = bm * 128 + wm * 64 + mi * 16 + l4 * 4 + r;
        int n = (bn & 7) * 128 + wn * 64 + ni * 16 + l15;
        int b = m >> 11, row = m & 2047, h = n >> 6, d = n & 63;
        u16 val = f2bf(acc[mi][ni][r]);
        size_t bh = (size_t)(b * 16 + h);
        if (which == 0)      qo[(bh * NSEQ + row) * 64 + d] = val;
        else if (which == 1) ko[(bh * NSEQ + row) * 64 + d] = val;
        else                 vo[(bh * 64 + d) * NSEQ + row] = val;
      }
}

// ---------------- final GEMM: out[m,n] = sum_k A[m,k]*W[n,k], fp32 out ----------------
__global__ __launch_bounds__(256) void gemm_out(const u16* __restrict__ A,
                                                const u16* __restrict__ W,
                                                float* __restrict__ C) {
  __shared__ __align__(16) u16 Al[128 * 64];
  __shared__ __align__(16) u16 Bl[128 * 64];
  const int tid = threadIdx.x;
  const int w = tid >> 6, l = tid & 63;
  const int l15 = l & 15, l4 = l >> 4;
  const int bm = blockIdx.x, bn = blockIdx.y;
  const int wm = w >> 1, wn = w & 1;

  f32x4 acc[4][4] = {};

  for (int ks = 0; ks < 1024; ks += 64) {
    __syncthreads();
#pragma unroll
    for (int c = 0; c < 4; ++c) {
      int g = w * 256 + c * 64 + l;
      int row = g >> 3, gc = g & 7;
      int sgc = gc ^ (row & 7);
      gload_lds16(A + (size_t)(bm * 128 + row) * 1024 + ks + sgc * 8, &Al[g * 8]);
      gload_lds16(W + (size_t)(bn * 128 + row) * 1024 + ks + sgc * 8, &Bl[g * 8]);
    }
    __syncthreads();
#pragma unroll
    for (int kc = 0; kc < 2; ++kc) {
      bf16x8 af[4], bfr[4];
#pragma unroll
      for (int mi = 0; mi < 4; ++mi) {
        int row = wm * 64 + mi * 16 + l15;
        int gc2 = (kc * 4 + l4) ^ (row & 7);
        af[mi] = *(const bf16x8*)&Al[row * 64 + gc2 * 8];
      }
#pragma unroll
      for (int ni = 0; ni < 4; ++ni) {
        int row = wn * 64 + ni * 16 + l15;
        int gc2 = (kc * 4 + l4) ^ (row & 7);
        bfr[ni] = *(const bf16x8*)&Bl[row * 64 + gc2 * 8];
      }
#pragma unroll
      for (int mi = 0; mi < 4; ++mi)
#pragma unroll
        for (int ni = 0; ni < 4; ++ni)
          acc[mi][ni] = __builtin_amdgcn_mfma_f32_16x16x32_bf16(af[mi], bfr[ni],
                                                                acc[mi][ni], 0, 0, 0);
    }
  }

#pragma unroll
  for (int mi = 0; mi < 4; ++mi)
#pragma unroll
    for (int ni = 0; ni < 4; ++ni)
#pragma unroll
      for (int r = 0; r < 4; ++r) {
        int m = bm * 128 + wm * 64 + mi * 16 + l4 * 4 + r;
        int n = bn * 128 + wn * 64 + ni * 16 + l15;
        C[(size_t)m * 1024 + n] = acc[mi][ni][r];
      }
}

// ---------------- flash attention (r3 schedule + conflict-free V) ----------------
// 256 thr = 4 waves x 16 q-rows, grid 2048, LDS K/V dbuf, ONE plain
// __syncthreads per body (r3 winner schedule; no setprio, no hand vmcnt).
// Swapped QK^T + register softmax (shfl_xor 16/32) + defer-max. K staged with
// row permutation so PV A-slots are standard: P feeds PV directly from cvt_pk
// regs and V is read as contiguous b128 (bank-conflict-free, same pattern as K).
// Batch-innermost XCD decode keeps alibi L2-resident (FETCH ~270 MB).
__global__ __launch_bounds__(256, 4) void attn_kernel(
    const u16* __restrict__ q, const u16* __restrict__ k, const u16* __restrict__ vT,
    const float* __restrict__ alibi, const u64* __restrict__ mbits,
    u16* __restrict__ o) {
  __shared__ __align__(16) u16 Kl[2][64 * 64];
  __shared__ __align__(16) u16 Vl[2][64 * 64];

  const int tid = threadIdx.x, w = tid >> 6, l = tid & 63;
  const int l15 = l & 15, l4 = l >> 4;
  const int W = blockIdx.x;
  const int W2 = (W & 7) * 256 + (W >> 3);
  // batch innermost: siblings b=0..3 dispatch-adjacent -> alibi L2 reuse
  const int b = W2 & 3, hq = W2 >> 2;
  const int qb = hq & 31, h = hq >> 5;
  const int bh = b * 16 + h;
  const int wq0 = qb * 64 + w * 16;
  const int myq = wq0 + l15;

  // Q fragment (B-operand: col q = l15)
  bf16x8 aq[2];
  {
    const u16* qrow = q + ((size_t)bh * NSEQ + myq) * 64;
    aq[0] = *(const bf16x8*)(qrow + l4 * 8);
    aq[1] = *(const bf16x8*)(qrow + 32 + l4 * 8);
  }

  // staging pointers. K rows permuted: LDS row p holds global row
  // 32*(p>>5) + 8*((p>>2)&3) + 4*((p>>4)&1) + (p&3)  -> S^T k-distribution
  // matches the standard PV A-slot order.
  const u16* kg[2]; const u16* vg[2];
#pragma unroll
  for (int c = 0; c < 2; ++c) {
    int g = w * 128 + c * 64 + l;
    int row = g >> 3, gc = g & 7, sgc = gc ^ (row & 7);
    int srow = (row & 0x23) | (((row >> 2) & 3) << 3) | (((row >> 4) & 1) << 2);
    kg[c] = k + ((size_t)bh * NSEQ + srow) * 64 + sgc * 8;
    vg[c] = vT + ((size_t)bh * 64 + row) * NSEQ + sgc * 8;
  }

  // per-lane alibi / mask pointers (permuted k: lane covers k = 32c + 8*l4 + 0..7)
  const float* alp = alibi + (size_t)h * NSEQ * NSEQ + (size_t)myq * NSEQ + 8 * l4;
  const u64* mrp = mbits + ((size_t)b * NSEQ + myq) * 32;

  // LDS read offsets (K and V identical pattern, conflict-free b128)
  const int kfr[2] = { l15 * 128 + (((0 + l4) ^ (l15 & 7)) << 4),
                       l15 * 128 + (((4 + l4) ^ (l15 & 7)) << 4) };

  f32x4 oacc[4] = {};          // q = wq0 + l4*4 + r, d = db*16 + l15
  float m_run = -3.0e38f, l_run = 0.f;

  auto stage = [&](u16* KB, u16* VB) {
#pragma unroll
    for (int c = 0; c < 2; ++c) {
      gload_lds16(kg[c], (char*)KB + (w * 128 + c * 64 + l) * 16);
      kg[c] += 4096;
      gload_lds16(vg[c], (char*)VB + (w * 128 + c * 64 + l) * 16);
      vg[c] += 64;
    }
  };

  stage(Kl[0], Vl[0]);
  __syncthreads();

  auto body = [&](const u16* KB, const u16* VB, u16* KN, u16* VN, int t, bool dost) {
    // current-tile bias/mask loads (issued first, consumed mid-body)
    float4 al[4];
    al[0] = *(const float4*)(alp + t * 64);
    al[1] = *(const float4*)(alp + t * 64 + 4);
    al[2] = *(const float4*)(alp + t * 64 + 32);
    al[3] = *(const float4*)(alp + t * 64 + 36);
    u64 mb = mrp[t];
    if (dost) stage(KN, VN);

    // S^T = K Q^T : lane q=l15; k rows permuted by staging
    f32x4 st[4];
#pragma unroll
    for (int kb = 0; kb < 4; ++kb) {
      f32x4 z = {0.f, 0.f, 0.f, 0.f};
      st[kb] = z;
#pragma unroll
      for (int kc = 0; kc < 2; ++kc) {
        bf16x8 bk = *(const bf16x8*)((const char*)KB + kfr[kc] + kb * 2048);
        st[kb] = __builtin_amdgcn_mfma_f32_16x16x32_bf16(bk, aq[kc], st[kb], 0, 0, 0);
      }
    }

    // scale + alibi (permuted layout: (kb,r) -> global k = 32*(kb>>1)+8*l4+4*(kb&1)+r)
#pragma unroll
    for (int kb = 0; kb < 4; ++kb)
#pragma unroll
      for (int r = 0; r < 4; ++r)
        st[kb][r] = fmaf(st[kb][r], ATT_SCALE, al[kb][r]);
    if (!__all(mb == ~0ull)) {
#pragma unroll
      for (int kb = 0; kb < 4; ++kb)
#pragma unroll
        for (int r = 0; r < 4; ++r) {
          int bit = 32 * (kb >> 1) + 8 * l4 + 4 * (kb & 1) + r;
          if (!((mb >> bit) & 1)) st[kb][r] = -3.0e38f;
        }
    }

    // row max: in-lane tree + xor16 + xor32
    float m0 = fmaxf(fmaxf(st[0][0], st[0][1]), fmaxf(st[0][2], st[0][3]));
    float m1 = fmaxf(fmaxf(st[1][0], st[1][1]), fmaxf(st[1][2], st[1][3]));
    float m2 = fmaxf(fmaxf(st[2][0], st[2][1]), fmaxf(st[2][2], st[2][3]));
    float m3 = fmaxf(fmaxf(st[3][0], st[3][1]), fmaxf(st[3][2], st[3][3]));
    float tm = fmaxf(fmaxf(m0, m1), fmaxf(m2, m3));
    tm = fmaxf(tm, __shfl_xor(tm, 16));
    tm = fmaxf(tm, __shfl_xor(tm, 32));

    // defer-max rescale
    if (__any(tm > m_run + 4.0f)) {
      float mn = fmaxf(m_run, tm);
      float fac = exp2f((m_run - mn) * LOG2E);
      l_run *= fac;
      m_run = mn;
#pragma unroll
      for (int r = 0; r < 4; ++r) {
        float fr = __shfl(fac, l4 * 4 + r);
#pragma unroll
        for (int db = 0; db < 4; ++db) oacc[db][r] *= fr;
      }
    }

    // exp + sum
    float negm = -m_run * LOG2E;
    float p[16];
#pragma unroll
    for (int kb = 0; kb < 4; ++kb)
#pragma unroll
      for (int r = 0; r < 4; ++r)
        p[kb * 4 + r] = exp2f(fmaf(st[kb][r], LOG2E, negm));
    float s0 = (p[0] + p[1]) + (p[2] + p[3]);
    float s1 = (p[4] + p[5]) + (p[6] + p[7]);
    float s2 = (p[8] + p[9]) + (p[10] + p[11]);
    float s3 = (p[12] + p[13]) + (p[14] + p[15]);
    float ts = (s0 + s1) + (s2 + s3);
    ts += __shfl_xor(ts, 16);
    ts += __shfl_xor(ts, 32);
    l_run += ts;

    // pack P -> bf16 pairs; standard A-slots: pa[c] slot j <-> global k = 32c+8*l4+j
    u32 Wp[8];
#pragma unroll
    for (int i = 0; i < 8; ++i)
      asm("v_cvt_pk_bf16_f32 %0, %1, %2" : "=v"(Wp[i]) : "v"(p[2 * i]), "v"(p[2 * i + 1]));

    // O += P V  (V as contiguous b128, conflict-free)
#pragma unroll
    for (int c = 0; c < 2; ++c) {
      u32x4 wv = {Wp[4 * c], Wp[4 * c + 1], Wp[4 * c + 2], Wp[4 * c + 3]};
      bf16x8 pa = __builtin_bit_cast(bf16x8, wv);
#pragma unroll
      for (int db = 0; db < 4; ++db) {
        bf16x8 bv = *(const bf16x8*)((const char*)VB + kfr[c] + db * 2048);
        oacc[db] = __builtin_amdgcn_mfma_f32_16x16x32_bf16(pa, bv, oacc[db], 0, 0, 0);
      }
    }
    __syncthreads();
  };

  for (int t2 = 0; t2 < 16; ++t2) {
    body(Kl[0], Vl[0], Kl[1], Vl[1], t2 * 2, true);
    body(Kl[1], Vl[1], Kl[0], Vl[0], t2 * 2 + 1, t2 < 15);
  }

  // normalize + write O (q = wq0 + l4*4 + r, d = db*16 + l15)
#pragma unroll
  for (int r = 0; r < 4; ++r) {
    float lr = __shfl(l_run, l4 * 4 + r);
    float inv = __builtin_amdgcn_rcpf(lr);
    int qq = wq0 + l4 * 4 + r;
#pragma unroll
    for (int db = 0; db < 4; ++db) {
      int d = db * 16 + l15;
      o[((size_t)b * NSEQ + qq) * DMODEL + h * 64 + d] = f2bf(oacc[db][r] * inv);
    }
  }
}

extern "C" void kernel_launch(void* const* d_in, const int* in_sizes, int n_in,
                              void* d_out, int out_size, void* d_ws, size_t ws_size,
                              hipStream_t stream) {
  (void)in_sizes; (void)n_in; (void)out_size; (void)ws_size;
  const float* x = (const float*)d_in[0];
  const int* mask = (const int*)d_in[1];
  const float* alibi = (const float*)d_in[2];
  const float* Wq = (const float*)d_in[3];
  const float* Wk = (const float*)d_in[4];
  const float* Wv = (const float*)d_in[5];
  const float* Wo = (const float*)d_in[6];
  float* out = (float*)d_out;

  char* ws = (char*)d_ws;
  const size_t MB = 1u << 20;
  u16* xb  = (u16*)(ws + 0 * MB);    // 16 MB
  u16* wqb = (u16*)(ws + 16 * MB);   // 8 MB (wq,wk,wv,wo contiguous)
  u16* wob = (u16*)(ws + 22 * MB);
  u16* qb  = (u16*)(ws + 24 * MB);   // 16 MB  [B,H,N,64]
  u16* kb  = (u16*)(ws + 40 * MB);   // 16 MB  [B,H,N,64]
  u16* vT  = (u16*)(ws + 56 * MB);   // 16 MB  [B,H,64,N]
  u16* ob  = (u16*)(ws + 72 * MB);   // 16 MB  [B,N,1024]
  u64* mbits = (u64*)(ws + 88 * MB); // 2 MB   [B*N][32]

  cast_f32_bf16<<<8192, 256, 0, stream>>>(x, xb, MTOT * DMODEL);
  cast_w4<<<4096, 256, 0, stream>>>(Wq, Wk, Wv, Wo, wqb);
  pack_mask<<<2048, 256, 0, stream>>>(mask, mbits);

  gemm_qkv<<<dim3(64, 24), 256, 0, stream>>>(xb, wqb, qb, kb, vT);

  attn_kernel<<<2048, 256, 0, stream>>>(qb, kb, vT, alibi, mbits, ob);

  gemm_out<<<dim3(64, 8), 256, 0, stream>>>(ob, wob, out);
}

// Round 10
// 361.898 us; speedup vs baseline: 2.0882x; 1.0417x over previous
//
#include <hip/hip_runtime.h>

#define NSEQ 2048
#define DMODEL 1024
#define NHEAD 16
#define HDIM 64
#define NBATCH 4
#define MTOT 8192
#define ATT_SCALE 0.125f
#define LOG2E 1.4426950408889634f
#define SM_SHIFT 12.0f

typedef __bf16 bf16x8 __attribute__((ext_vector_type(8)));
typedef float f32x4 __attribute__((ext_vector_type(4)));
typedef unsigned int u32x4 __attribute__((ext_vector_type(4)));
typedef unsigned short u16;
typedef unsigned int u32;
typedef unsigned long long u64;

__device__ __forceinline__ u16 f2bf(float f) {
  u32 u = __builtin_bit_cast(u32, f);
  return (u16)((u + 0x7fffu + ((u >> 16) & 1u)) >> 16);
}

__device__ __forceinline__ void gload_lds16(const void* g, void* l) {
  __builtin_amdgcn_global_load_lds(
      (__attribute__((address_space(1))) const u32*)g,
      (__attribute__((address_space(3))) u32*)l, 16, 0, 0);
}

// ---------------- cast fp32 -> bf16 (x) ----------------
__global__ __launch_bounds__(256) void cast_f32_bf16(const float* __restrict__ in,
                                                     u16* __restrict__ out, int n) {
  int i = (blockIdx.x * 256 + threadIdx.x) * 4;
  if (i >= n) return;
  float4 v = *(const float4*)(in + i);
  ushort4 o;
  o.x = f2bf(v.x); o.y = f2bf(v.y); o.z = f2bf(v.z); o.w = f2bf(v.w);
  *(ushort4*)(out + i) = o;
}

// ---------------- cast 4 weights -> contiguous bf16 block ----------------
__global__ __launch_bounds__(256) void cast_w4(const float* __restrict__ a,
                                               const float* __restrict__ b,
                                               const float* __restrict__ c,
                                               const float* __restrict__ d,
                                               u16* __restrict__ out) {
  int bid = blockIdx.x;
  int which = bid >> 10, lb = bid & 1023;
  const float* src = (which == 0) ? a : (which == 1) ? b : (which == 2) ? c : d;
  int i = (lb * 256 + threadIdx.x) * 4;
  float4 v = *(const float4*)(src + i);
  ushort4 o;
  o.x = f2bf(v.x); o.y = f2bf(v.y); o.z = f2bf(v.z); o.w = f2bf(v.w);
  *(ushort4*)(out + (size_t)which * 1048576 + i) = o;
}

// ---------------- pack mask int32 -> bit per element ----------------
__global__ __launch_bounds__(256) void pack_mask(const int* __restrict__ mask,
                                                 u64* __restrict__ bits) {
  int wave = (blockIdx.x * 256 + threadIdx.x) >> 6;
  int lane = threadIdx.x & 63;
  const int* row = mask + (size_t)wave * NSEQ;
  u64* out = bits + (size_t)wave * 32;
  for (int c = 0; c < 32; ++c) {
    int v = row[c * 64 + lane];
    u64 bl = __ballot(v != 0);
    if (lane == 0) out[c] = bl;
  }
}

// ---------------- fused QKV GEMM: C[m,n] = sum_k A[m,k]*Wc[n,k], N=3072 ----------------
// bn 0..7 -> Q [B,H,N,64]; 8..15 -> K [B,H,N,64]; 16..23 -> V^T [B,H,64,NSEQ]
__global__ __launch_bounds__(256) void gemm_qkv(const u16* __restrict__ A,
                                                const u16* __restrict__ Wc,
                                                u16* __restrict__ qo,
                                                u16* __restrict__ ko,
                                                u16* __restrict__ vo) {
  __shared__ __align__(16) u16 Al[128 * 64];
  __shared__ __align__(16) u16 Bl[128 * 64];
  const int tid = threadIdx.x;
  const int w = tid >> 6, l = tid & 63;
  const int l15 = l & 15, l4 = l >> 4;
  const int bm = blockIdx.x, bn = blockIdx.y;
  const int wm = w >> 1, wn = w & 1;

  f32x4 acc[4][4] = {};

  for (int ks = 0; ks < 1024; ks += 64) {
    __syncthreads();
#pragma unroll
    for (int c = 0; c < 4; ++c) {
      int g = w * 256 + c * 64 + l;
      int row = g >> 3, gc = g & 7;
      int sgc = gc ^ (row & 7);
      gload_lds16(A + (size_t)(bm * 128 + row) * 1024 + ks + sgc * 8, &Al[g * 8]);
      gload_lds16(Wc + (size_t)(bn * 128 + row) * 1024 + ks + sgc * 8, &Bl[g * 8]);
    }
    __syncthreads();
#pragma unroll
    for (int kc = 0; kc < 2; ++kc) {
      bf16x8 af[4], bfr[4];
#pragma unroll
      for (int mi = 0; mi < 4; ++mi) {
        int row = wm * 64 + mi * 16 + l15;
        int gc2 = (kc * 4 + l4) ^ (row & 7);
        af[mi] = *(const bf16x8*)&Al[row * 64 + gc2 * 8];
      }
#pragma unroll
      for (int ni = 0; ni < 4; ++ni) {
        int row = wn * 64 + ni * 16 + l15;
        int gc2 = (kc * 4 + l4) ^ (row & 7);
        bfr[ni] = *(const bf16x8*)&Bl[row * 64 + gc2 * 8];
      }
#pragma unroll
      for (int mi = 0; mi < 4; ++mi)
#pragma unroll
        for (int ni = 0; ni < 4; ++ni)
          acc[mi][ni] = __builtin_amdgcn_mfma_f32_16x16x32_bf16(af[mi], bfr[ni],
                                                                acc[mi][ni], 0, 0, 0);
    }
  }

  const int which = bn >> 3;
#pragma unroll
  for (int mi = 0; mi < 4; ++mi)
#pragma unroll
    for (int ni = 0; ni < 4; ++ni)
#pragma unroll
      for (int r = 0; r < 4; ++r) {
        int m = bm * 128 + wm * 64 + mi * 16 + l4 * 4 + r;
        int n = (bn & 7) * 128 + wn * 64 + ni * 16 + l15;
        int b = m >> 11, row = m & 2047, h = n >> 6, d = n & 63;
        u16 val = f2bf(acc[mi][ni][r]);
        size_t bh = (size_t)(b * 16 + h);
        if (which == 0)      qo[(bh * NSEQ + row) * 64 + d] = val;
        else if (which == 1) ko[(bh * NSEQ + row) * 64 + d] = val;
        else                 vo[(bh * 64 + d) * NSEQ + row] = val;
      }
}

// ---------------- final GEMM: out[m,n] = sum_k A[m,k]*W[n,k], fp32 out ----------------
__global__ __launch_bounds__(256) void gemm_out(const u16* __restrict__ A,
                                                const u16* __restrict__ W,
                                                float* __restrict__ C) {
  __shared__ __align__(16) u16 Al[128 * 64];
  __shared__ __align__(16) u16 Bl[128 * 64];
  const int tid = threadIdx.x;
  const int w = tid >> 6, l = tid & 63;
  const int l15 = l & 15, l4 = l >> 4;
  const int bm = blockIdx.x, bn = blockIdx.y;
  const int wm = w >> 1, wn = w & 1;

  f32x4 acc[4][4] = {};

  for (int ks = 0; ks < 1024; ks += 64) {
    __syncthreads();
#pragma unroll
    for (int c = 0; c < 4; ++c) {
      int g = w * 256 + c * 64 + l;
      int row = g >> 3, gc = g & 7;
      int sgc = gc ^ (row & 7);
      gload_lds16(A + (size_t)(bm * 128 + row) * 1024 + ks + sgc * 8, &Al[g * 8]);
      gload_lds16(W + (size_t)(bn * 128 + row) * 1024 + ks + sgc * 8, &Bl[g * 8]);
    }
    __syncthreads();
#pragma unroll
    for (int kc = 0; kc < 2; ++kc) {
      bf16x8 af[4], bfr[4];
#pragma unroll
      for (int mi = 0; mi < 4; ++mi) {
        int row = wm * 64 + mi * 16 + l15;
        int gc2 = (kc * 4 + l4) ^ (row & 7);
        af[mi] = *(const bf16x8*)&Al[row * 64 + gc2 * 8];
      }
#pragma unroll
      for (int ni = 0; ni < 4; ++ni) {
        int row = wn * 64 + ni * 16 + l15;
        int gc2 = (kc * 4 + l4) ^ (row & 7);
        bfr[ni] = *(const bf16x8*)&Bl[row * 64 + gc2 * 8];
      }
#pragma unroll
      for (int mi = 0; mi < 4; ++mi)
#pragma unroll
        for (int ni = 0; ni < 4; ++ni)
          acc[mi][ni] = __builtin_amdgcn_mfma_f32_16x16x32_bf16(af[mi], bfr[ni],
                                                                acc[mi][ni], 0, 0, 0);
    }
  }

#pragma unroll
  for (int mi = 0; mi < 4; ++mi)
#pragma unroll
    for (int ni = 0; ni < 4; ++ni)
#pragma unroll
      for (int r = 0; r < 4; ++r) {
        int m = bm * 128 + wm * 64 + mi * 16 + l4 * 4 + r;
        int n = bn * 128 + wn * 64 + ni * 16 + l15;
        C[(size_t)m * 1024 + n] = acc[mi][ni][r];
      }
}

// ---------------- flash attention (r9 structure + VALU-free softmax) ----------------
// 256 thr = 4 waves x 16 q-rows, grid 2048, LDS K/V dbuf, ONE plain
// __syncthreads per body. Swapped QK^T; FIXED-SHIFT softmax (shift-invariant,
// no max / no shfl): p = exp2((S-12)*log2e). Row-sum via MFMA ones-trick into
// osum (same layout as oacc -> epilogue shfl-free). K staged with row
// permutation so PV A-slots are standard; V read as contiguous b128
// (conflict-free). Alibi/mask current-t single-buffered (NO reg double-buffer
// -> no spill; r7's 150 MB scratch WRITE came from that). Batch-innermost XCD
// decode keeps alibi L2-shared across the 4 batch siblings.
__global__ __launch_bounds__(256, 4) void attn_kernel(
    const u16* __restrict__ q, const u16* __restrict__ k, const u16* __restrict__ vT,
    const float* __restrict__ alibi, const u64* __restrict__ mbits,
    u16* __restrict__ o) {
  __shared__ __align__(16) u16 Kl[2][64 * 64];
  __shared__ __align__(16) u16 Vl[2][64 * 64];

  const int tid = threadIdx.x, w = tid >> 6, l = tid & 63;
  const int l15 = l & 15, l4 = l >> 4;
  const int W = blockIdx.x;
  const int W2 = (W & 7) * 256 + (W >> 3);
  // batch innermost: siblings b=0..3 dispatch-adjacent -> alibi L2 reuse
  const int b = W2 & 3, hq = W2 >> 2;
  const int qb = hq & 31, h = hq >> 5;
  const int bh = b * 16 + h;
  const int wq0 = qb * 64 + w * 16;
  const int myq = wq0 + l15;

  // Q fragment (B-operand: col q = l15)
  bf16x8 aq[2];
  {
    const u16* qrow = q + ((size_t)bh * NSEQ + myq) * 64;
    aq[0] = *(const bf16x8*)(qrow + l4 * 8);
    aq[1] = *(const bf16x8*)(qrow + 32 + l4 * 8);
  }

  // staging pointers. K rows permuted: LDS row p holds global row
  // 32*(p>>5) + 8*((p>>2)&3) + 4*((p>>4)&1) + (p&3)  -> S^T k-distribution
  // matches the standard PV A-slot order.
  const u16* kg[2]; const u16* vg[2];
#pragma unroll
  for (int c = 0; c < 2; ++c) {
    int g = w * 128 + c * 64 + l;
    int row = g >> 3, gc = g & 7, sgc = gc ^ (row & 7);
    int srow = (row & 0x23) | (((row >> 2) & 3) << 3) | (((row >> 4) & 1) << 2);
    kg[c] = k + ((size_t)bh * NSEQ + srow) * 64 + sgc * 8;
    vg[c] = vT + ((size_t)bh * 64 + row) * NSEQ + sgc * 8;
  }

  // per-lane alibi / mask pointers (permuted k: lane covers k = 32c + 8*l4 + 0..7)
  const float* alp = alibi + (size_t)h * NSEQ * NSEQ + (size_t)myq * NSEQ + 8 * l4;
  const u64* mrp = mbits + ((size_t)b * NSEQ + myq) * 32;

  // LDS read offsets (K and V identical pattern, conflict-free b128)
  const int kfr[2] = { l15 * 128 + (((0 + l4) ^ (l15 & 7)) << 4),
                       l15 * 128 + (((4 + l4) ^ (l15 & 7)) << 4) };

  // all-ones bf16 B-fragment for the row-sum MFMA
  const u32x4 onesu = {0x3F803F80u, 0x3F803F80u, 0x3F803F80u, 0x3F803F80u};
  const bf16x8 bones = __builtin_bit_cast(bf16x8, onesu);

  f32x4 oacc[4] = {};          // q = wq0 + l4*4 + r, d = db*16 + l15
  f32x4 osum = {};             // row sums of P, same q mapping

  auto stage = [&](u16* KB, u16* VB) {
#pragma unroll
    for (int c = 0; c < 2; ++c) {
      gload_lds16(kg[c], (char*)KB + (w * 128 + c * 64 + l) * 16);
      kg[c] += 4096;
      gload_lds16(vg[c], (char*)VB + (w * 128 + c * 64 + l) * 16);
      vg[c] += 64;
    }
  };

  stage(Kl[0], Vl[0]);
  __syncthreads();

  auto body = [&](const u16* KB, const u16* VB, u16* KN, u16* VN, int t, bool dost) {
    // current-tile bias/mask loads (issued first, consumed after QK^T)
    float4 al[4];
    al[0] = *(const float4*)(alp + t * 64);
    al[1] = *(const float4*)(alp + t * 64 + 4);
    al[2] = *(const float4*)(alp + t * 64 + 32);
    al[3] = *(const float4*)(alp + t * 64 + 36);
    u64 mb = mrp[t];
    if (dost) stage(KN, VN);

    // S^T = K Q^T : lane q=l15; k rows permuted by staging
    f32x4 st[4];
#pragma unroll
    for (int kb = 0; kb < 4; ++kb) {
      f32x4 z = {0.f, 0.f, 0.f, 0.f};
      st[kb] = z;
#pragma unroll
      for (int kc = 0; kc < 2; ++kc) {
        bf16x8 bk = *(const bf16x8*)((const char*)KB + kfr[kc] + kb * 2048);
        st[kb] = __builtin_amdgcn_mfma_f32_16x16x32_bf16(bk, aq[kc], st[kb], 0, 0, 0);
      }
    }

    // scale + alibi (permuted layout: (kb,r) -> global k = 32*(kb>>1)+8*l4+4*(kb&1)+r)
#pragma unroll
    for (int kb = 0; kb < 4; ++kb)
#pragma unroll
      for (int r = 0; r < 4; ++r)
        st[kb][r] = fmaf(st[kb][r], ATT_SCALE, al[kb][r]);
    if (!__all(mb == ~0ull)) {
#pragma unroll
      for (int kb = 0; kb < 4; ++kb)
#pragma unroll
        for (int r = 0; r < 4; ++r) {
          int bit = 32 * (kb >> 1) + 8 * l4 + 4 * (kb & 1) + r;
          if (!((mb >> bit) & 1)) st[kb][r] = -3.0e38f;
        }
    }

    // fixed-shift exp: p = exp2(S*log2e - 12*log2e). No max, no shfl, no rescale.
    float p[16];
#pragma unroll
    for (int kb = 0; kb < 4; ++kb)
#pragma unroll
      for (int r = 0; r < 4; ++r)
        p[kb * 4 + r] = exp2f(fmaf(st[kb][r], LOG2E, -SM_SHIFT * LOG2E));

    // pack P -> bf16 pairs; standard A-slots: pa[c] slot j <-> global k = 32c+8*l4+j
    u32 Wp[8];
#pragma unroll
    for (int i = 0; i < 8; ++i)
      asm("v_cvt_pk_bf16_f32 %0, %1, %2" : "=v"(Wp[i]) : "v"(p[2 * i]), "v"(p[2 * i + 1]));

    // O += P V ; row-sum += P * 1 (ones-trick, lands in oacc layout)
#pragma unroll
    for (int c = 0; c < 2; ++c) {
      u32x4 wv = {Wp[4 * c], Wp[4 * c + 1], Wp[4 * c + 2], Wp[4 * c + 3]};
      bf16x8 pa = __builtin_bit_cast(bf16x8, wv);
      osum = __builtin_amdgcn_mfma_f32_16x16x32_bf16(pa, bones, osum, 0, 0, 0);
#pragma unroll
      for (int db = 0; db < 4; ++db) {
        bf16x8 bv = *(const bf16x8*)((const char*)VB + kfr[c] + db * 2048);
        oacc[db] = __builtin_amdgcn_mfma_f32_16x16x32_bf16(pa, bv, oacc[db], 0, 0, 0);
      }
    }
    __syncthreads();
  };

  for (int t2 = 0; t2 < 16; ++t2) {
    body(Kl[0], Vl[0], Kl[1], Vl[1], t2 * 2, true);
    body(Kl[1], Vl[1], Kl[0], Vl[0], t2 * 2 + 1, t2 < 15);
  }

  // normalize + write O (q = wq0 + l4*4 + r, d = db*16 + l15); shfl-free
#pragma unroll
  for (int r = 0; r < 4; ++r) {
    float inv = __builtin_amdgcn_rcpf(osum[r]);
    int qq = wq0 + l4 * 4 + r;
#pragma unroll
    for (int db = 0; db < 4; ++db) {
      int d = db * 16 + l15;
      o[((size_t)b * NSEQ + qq) * DMODEL + h * 64 + d] = f2bf(oacc[db][r] * inv);
    }
  }
}

extern "C" void kernel_launch(void* const* d_in, const int* in_sizes, int n_in,
                              void* d_out, int out_size, void* d_ws, size_t ws_size,
                              hipStream_t stream) {
  (void)in_sizes; (void)n_in; (void)out_size; (void)ws_size;
  const float* x = (const float*)d_in[0];
  const int* mask = (const int*)d_in[1];
  const float* alibi = (const float*)d_in[2];
  const float* Wq = (const float*)d_in[3];
  const float* Wk = (const float*)d_in[4];
  const float* Wv = (const float*)d_in[5];
  const float* Wo = (const float*)d_in[6];
  float* out = (float*)d_out;

  char* ws = (char*)d_ws;
  const size_t MB = 1u << 20;
  u16* xb  = (u16*)(ws + 0 * MB);    // 16 MB
  u16* wqb = (u16*)(ws + 16 * MB);   // 8 MB (wq,wk,wv,wo contiguous)
  u16* wob = (u16*)(ws + 22 * MB);
  u16* qb  = (u16*)(ws + 24 * MB);   // 16 MB  [B,H,N,64]
  u16* kb  = (u16*)(ws + 40 * MB);   // 16 MB  [B,H,N,64]
  u16* vT  = (u16*)(ws + 56 * MB);   // 16 MB  [B,H,64,N]
  u16* ob  = (u16*)(ws + 72 * MB);   // 16 MB  [B,N,1024]
  u64* mbits = (u64*)(ws + 88 * MB); // 2 MB   [B*N][32]

  cast_f32_bf16<<<8192, 256, 0, stream>>>(x, xb, MTOT * DMODEL);
  cast_w4<<<4096, 256, 0, stream>>>(Wq, Wk, Wv, Wo, wqb);
  pack_mask<<<2048, 256, 0, stream>>>(mask, mbits);

  gemm_qkv<<<dim3(64, 24), 256, 0, stream>>>(xb, wqb, qb, kb, vT);

  attn_kernel<<<2048, 256, 0, stream>>>(qb, kb, vT, alibi, mbits, ob);

  gemm_out<<<dim3(64, 8), 256, 0, stream>>>(ob, wob, out);
}